// Round 14
// baseline (291.067 us; speedup 1.0000x reference)
//
#include <hip/hip_runtime.h>

#define N_TOK 4096
#define DMODEL 1024
#define NEXP 16
#define HDIM 2048
#define CAP 1024

typedef __attribute__((ext_vector_type(8))) short frag8;      // 8 bf16 MFMA operand
typedef __attribute__((ext_vector_type(4))) float f32x4;      // MFMA accumulator
typedef __attribute__((ext_vector_type(8))) unsigned short us8;

__device__ __forceinline__ unsigned short f2bf(float x) {
  unsigned u = __builtin_bit_cast(unsigned, x);
  u += 0x7fffu + ((u >> 16) & 1u);           // RNE
  return (unsigned short)(u >> 16);
}
__device__ __forceinline__ float bf2f(unsigned short b) {
  unsigned u = ((unsigned)b) << 16;
  return __builtin_bit_cast(float, u);
}
__device__ __forceinline__ void load_lds16(const void* g, void* l) {
  __builtin_amdgcn_global_load_lds((const __attribute__((address_space(1))) void*)g,
                                   (__attribute__((address_space(3))) void*)l, 16, 0, 0);
}
#define SBAR0 __builtin_amdgcn_sched_barrier(0)

// ---------------- gate phase 1: logits -> top2 -> softmax (NO atomics) [R2-verified] ----------------
__global__ __launch_bounds__(256) void gate_logits_kernel(
    const float* __restrict__ x, const float* __restrict__ Wg, const float* __restrict__ bg,
    int* __restrict__ a_e, float* __restrict__ a_gate)
{
  int wid = threadIdx.x >> 6, l = threadIdx.x & 63;
  int n = blockIdx.x * 4 + wid;
  const float* xr = x + (size_t)n * DMODEL;
  float acc[NEXP];
#pragma unroll
  for (int e = 0; e < NEXP; ++e) acc[e] = 0.f;
#pragma unroll
  for (int q = 0; q < 4; ++q) {
    float4 xv = *(const float4*)(xr + q * 256 + l * 4);
    const float* wr = Wg + (size_t)(q * 256 + l * 4) * NEXP;
#pragma unroll
    for (int j = 0; j < 4; ++j) {
      float xs = j == 0 ? xv.x : j == 1 ? xv.y : j == 2 ? xv.z : xv.w;
      const float4* w4 = (const float4*)(wr + j * NEXP);
#pragma unroll
      for (int qq = 0; qq < 4; ++qq) {
        float4 w = w4[qq];
        acc[qq*4+0] += xs * w.x; acc[qq*4+1] += xs * w.y;
        acc[qq*4+2] += xs * w.z; acc[qq*4+3] += xs * w.w;
      }
    }
  }
#pragma unroll
  for (int e = 0; e < NEXP; ++e) {
    float v = acc[e];
#pragma unroll
    for (int off = 32; off > 0; off >>= 1) v += __shfl_xor(v, off, 64);
    acc[e] = v + bg[e];
  }
  if (l == 0) {
    int i1 = 0; float v1 = acc[0];
#pragma unroll
    for (int e = 1; e < NEXP; ++e) if (acc[e] > v1) { v1 = acc[e]; i1 = e; }
    int i2 = -1; float v2 = -1e30f;
#pragma unroll
    for (int e = 0; e < NEXP; ++e) if (e != i1 && acc[e] > v2) { v2 = acc[e]; i2 = e; }
    float e2 = __expf(v2 - v1);
    float inv = 1.f / (1.f + e2);
    a_e[n*2] = i1;   a_gate[n*2] = inv;
    a_e[n*2+1] = i2; a_gate[n*2+1] = e2 * inv;
  }
}

// ---------------- gate phase 2: per-expert slot assignment [R2-verified] ----------------
__global__ __launch_bounds__(256) void assign_kernel(
    const int* __restrict__ a_e, int* __restrict__ a_slot,
    int* __restrict__ tok_of_slot, int* __restrict__ cnt)
{
  __shared__ int c;
  if (threadIdx.x == 0) c = 0;
  __syncthreads();
  int eid = blockIdx.x;
  for (int j = threadIdx.x; j < N_TOK * 2; j += 256) {
    if (a_e[j] == eid) {
      int p = atomicAdd(&c, 1);
      a_slot[j] = p;
      if (p < CAP) tok_of_slot[eid * CAP + p] = j >> 1;
    }
  }
  __syncthreads();
  if (threadIdx.x == 0) cnt[eid] = c;
}

// ---------------- gather: x rows -> bf16 images [e][rt:8][kt:16][128][64] [R2-verified] ----------------
__global__ __launch_bounds__(256) void gather_kernel(
    const float* __restrict__ x, const int* __restrict__ cnt,
    const int* __restrict__ tok_of_slot, unsigned short* __restrict__ Xe)
{
  int rid = blockIdx.x * 2 + (threadIdx.x >> 7);
  int tl = threadIdx.x & 127;
  int e = rid >> 10, slot = rid & (CAP - 1);
  int c = cnt[e]; if (c > CAP) c = CAP;
  if (slot >= c) return;
  int tok = tok_of_slot[rid];
  const float4* xs = (const float4*)(x + (size_t)tok * DMODEL + tl * 8);
  float4 u = xs[0], v = xs[1];
  us8 p;
  p[0]=f2bf(u.x); p[1]=f2bf(u.y); p[2]=f2bf(u.z); p[3]=f2bf(u.w);
  p[4]=f2bf(v.x); p[5]=f2bf(v.y); p[6]=f2bf(v.z); p[7]=f2bf(v.w);
  int kt = tl >> 3, s = tl & 7;
  int row = slot & 127, rt = slot >> 7;
  size_t off = ((size_t)((e*8 + rt)*16 + kt)) * 8192 + (size_t)row*64 + ((s ^ (row & 7)) << 3);
  *(us8*)&Xe[off] = p;
}

// ---------------- prepack: f32 [E][R][C] -> bf16 images logical [C][R] [R2-verified] ----------------
__global__ __launch_bounds__(256) void prepack_kernel(
    const float* __restrict__ src, unsigned short* __restrict__ dst, int R, int C)
{
  __shared__ float tr[64 * 133];
  int nrt = C >> 7, nkt = R >> 6;
  int bid = blockIdx.x;
  int e = bid / (nrt * nkt), rem = bid % (nrt * nkt);
  int rt = rem / nkt, kt = rem % nkt;
  int t = threadIdx.x;
  int r0 = kt * 64, c0 = rt * 128;
  const float* sp = src + ((size_t)e * R + r0) * C + c0;
#pragma unroll
  for (int i = 0; i < 8; ++i) {
    int row = i * 8 + (t >> 5), col = (t & 31) * 4;
    float4 v = *(const float4*)(sp + (size_t)row * C + col);
    float* d = &tr[row * 133 + col];
    d[0] = v.x; d[1] = v.y; d[2] = v.z; d[3] = v.w;
  }
  __syncthreads();
  size_t obase = ((size_t)(e * nrt + rt) * nkt + kt) * 8192;
#pragma unroll
  for (int q = 0; q < 4; ++q) {
    int chunk = q * 256 + t;
    int orow = chunk >> 3, sl = chunk & 7;
    us8 p;
#pragma unroll
    for (int j = 0; j < 8; ++j) p[j] = f2bf(tr[(sl*8 + j)*133 + orow]);
    *(us8*)&dst[obase + (size_t)orow*64 + ((sl ^ (orow & 7)) << 3)] = p;
  }
}

// ---------------- grouped GEMM: 256x256 tile, 8 waves (2Mx4N), BK=64, all-gload_lds ----------------
// A,B: pre-swizzled bf16 16KB images. LDS: 2 buffers x (A0|A1|B0|B1) = 128KB.
// Counted pipeline (R13-proven contract): per iter exactly 8 gload_lds/thread;
// vmcnt(8) waits the PREVIOUS iter's stage (full-iteration lookahead). 2 barriers/iter.
template<int KT, int NTG, bool GELU, bool OUT_BLOCKED>
__global__ __launch_bounds__(512, 1) void gemm_kernel(
    const unsigned short* __restrict__ Aimg, const unsigned short* __restrict__ Bimg,
    unsigned short* __restrict__ OutU, const float* __restrict__ bias,
    const int* __restrict__ cnt)
{
  constexpr int LDW = NTG * 256;
  constexpr int NBLK = NEXP * NTG * 4;
  __shared__ __align__(16) char smem[131072];
  int bid = blockIdx.x;
  int item = (bid & 7) * (NBLK / 8) + (bid >> 3);   // XCD-chunked
  int e = item / (NTG * 4), rem = item % (NTG * 4);
  int nt = rem >> 2, mtg = rem & 3;                 // mtg innermost: B-slab L2 reuse
  int mcnt = cnt[e]; if (mcnt > CAP) mcnt = CAP;
  if (mtg * 256 >= mcnt) return;
  int t = threadIdx.x, l = t & 63, w = t >> 6;
  int wm = w >> 2, wn = w & 3;
  int rA = l & 15, g = l >> 4, r7 = rA & 7;
  int sw0 = (g ^ r7) << 4, sw1 = ((g + 4) ^ r7) << 4;

  const char* sA0 = (const char*)(Aimg + (size_t)((e * 8 + mtg * 2 + 0) * KT) * 8192);
  const char* sA1 = (const char*)(Aimg + (size_t)((e * 8 + mtg * 2 + 1) * KT) * 8192);
  const char* sB0 = (const char*)(Bimg + (size_t)((e * (NTG * 2) + nt * 2 + 0) * KT) * 8192);
  const char* sB1 = (const char*)(Bimg + (size_t)((e * (NTG * 2) + nt * 2 + 1) * KT) * 8192);
  int ls = t * 16;                                  // 512 threads x 16B = 8KB per call

  auto stage = [&](int bv, int kt) {                // 8 gload_lds/thread = 64KB/block
    char* d = smem + bv * 65536;
    const char* a0 = sA0 + (size_t)kt * 16384;
    const char* a1 = sA1 + (size_t)kt * 16384;
    const char* b0 = sB0 + (size_t)kt * 16384;
    const char* b1 = sB1 + (size_t)kt * 16384;
    load_lds16(a0 + ls,        d + ls);
    load_lds16(a0 + 8192 + ls, d + 8192 + ls);
    load_lds16(a1 + ls,        d + 16384 + ls);
    load_lds16(a1 + 8192 + ls, d + 24576 + ls);
    load_lds16(b0 + ls,        d + 32768 + ls);
    load_lds16(b0 + 8192 + ls, d + 40960 + ls);
    load_lds16(b1 + ls,        d + 49152 + ls);
    load_lds16(b1 + 8192 + ls, d + 57344 + ls);
  };

  f32x4 acc[8][4] = {};
  int aOff = wm * 16384 + rA * 128;
  int bOff = 32768 + (wn >> 1) * 16384 + ((wn & 1) * 64 + rA) * 128;

  auto compute = [&](int bv) {
    const char* bA = smem + bv * 65536 + aOff;
    const char* bB = smem + bv * 65536 + bOff;
    frag8 bfr[4][2];
#pragma unroll
    for (int n16 = 0; n16 < 4; ++n16) {
      bfr[n16][0] = *(const frag8*)(bB + n16 * 2048 + sw0);
      bfr[n16][1] = *(const frag8*)(bB + n16 * 2048 + sw1);
    }
    __builtin_amdgcn_s_setprio(1);
#pragma unroll
    for (int m16 = 0; m16 < 8; ++m16) {
      frag8 a0 = *(const frag8*)(bA + m16 * 2048 + sw0);
      frag8 a1 = *(const frag8*)(bA + m16 * 2048 + sw1);
#pragma unroll
      for (int n16 = 0; n16 < 4; ++n16) {
        acc[m16][n16] = __builtin_amdgcn_mfma_f32_16x16x32_bf16(a0, bfr[n16][0], acc[m16][n16], 0, 0, 0);
        acc[m16][n16] = __builtin_amdgcn_mfma_f32_16x16x32_bf16(a1, bfr[n16][1], acc[m16][n16], 0, 0, 0);
      }
    }
    __builtin_amdgcn_s_setprio(0);
  };

  // ---- prologue: invariant at iter kt: buf kt&1 = tile kt (landed); stage(kt+1) in flight ----
  stage(0, 0); SBAR0;
  stage(1, KT > 1 ? 1 : 0); SBAR0;
  asm volatile("s_waitcnt vmcnt(8)" ::: "memory");   // tile0 landed (8 newest = stage(1))
  SBAR0; __builtin_amdgcn_s_barrier(); SBAR0;

  for (int kt = 0; kt < KT; ++kt) {
    compute(kt & 1);
    if (kt + 1 < KT) {
      SBAR0; __builtin_amdgcn_s_barrier(); SBAR0;    // all waves done reading buf kt&1
      int k2 = (kt + 2 < KT) ? kt + 2 : KT - 1;      // clamped: uniform vm counts
      stage(kt & 1, k2); SBAR0;
      asm volatile("s_waitcnt vmcnt(8)" ::: "memory");  // stage(kt+1) done (issued prev iter)
      SBAR0; __builtin_amdgcn_s_barrier(); SBAR0;    // buf kt+1 ready
    }
  }
  asm volatile("s_waitcnt vmcnt(0)" ::: "memory");   // drain clamped redundant DMA
  asm volatile("s_waitcnt lgkmcnt(0)" ::: "memory");
  SBAR0; __builtin_amdgcn_s_barrier(); SBAR0;        // LDS dead; reuse as epilogue bounce

  float bv[4];
#pragma unroll
  for (int n16 = 0; n16 < 4; ++n16)
    bv[n16] = bias[e * LDW + nt * 256 + wn * 64 + n16 * 16 + rA];

  char* wb = smem + w * 16384;                       // per-wave 128x64 bf16 bounce (16KB)
  if constexpr (OUT_BLOCKED) {
    // gelu -> bf16 -> swizzled [128][64] image -> hB images [e][mi:8][chunk:NTG*4][128][64]
#pragma unroll
    for (int m16 = 0; m16 < 8; ++m16)
#pragma unroll
      for (int n16 = 0; n16 < 4; ++n16)
#pragma unroll
        for (int rr = 0; rr < 4; ++rr) {
          float xv = acc[m16][n16][rr] + bv[n16];
          if (GELU) {
            float u = 0.7978845608028654f * (xv + 0.044715f * xv * xv * xv);
            xv = xv / (1.f + __expf(-2.f * u));      // x*sigmoid(2u) == gelu_tanh
          }
          int row = m16 * 16 + g * 4 + rr;           // 0..127
          int col = n16 * 16 + rA;                   // 0..63
          *(unsigned short*)(wb + row * 128 + (((col >> 3) ^ (row & 7)) << 4) + (col & 7) * 2) = f2bf(xv);
        }
    asm volatile("s_waitcnt lgkmcnt(0)" ::: "memory");
    size_t ib = ((size_t)(e * 8 + mtg * 2 + wm) * (NTG * 4) + nt * 4 + wn) * 8192;
#pragma unroll
    for (int it = 0; it < 16; ++it) {
      int row = it * 8 + (l >> 3), p = l & 7;        // phys slot == out phys slot (XORs cancel)
      us8 v = *(const us8*)(wb + row * 128 + p * 16);
      *(us8*)&OutU[ib + (size_t)row * 64 + p * 8] = v;
    }
  } else {
    // linear bf16 out [e][CAP][LDW]
#pragma unroll
    for (int m16 = 0; m16 < 8; ++m16)
#pragma unroll
      for (int n16 = 0; n16 < 4; ++n16)
#pragma unroll
        for (int rr = 0; rr < 4; ++rr) {
          int row = m16 * 16 + g * 4 + rr;
          int col = n16 * 16 + rA;
          *(unsigned short*)(wb + row * 128 + col * 2) = f2bf(acc[m16][n16][rr] + bv[n16]);
        }
    asm volatile("s_waitcnt lgkmcnt(0)" ::: "memory");
#pragma unroll
    for (int it = 0; it < 16; ++it) {
      int row = it * 8 + (l >> 3), p = l & 7;
      us8 v = *(const us8*)(wb + row * 128 + p * 16);
      *(us8*)&OutU[(size_t)(e * CAP + mtg * 256 + wm * 128 + row) * LDW
                   + nt * 256 + wn * 64 + p * 8] = v;
    }
  }
}

// ---------------- combine: out[n] = g0*ye[e0][s0] + g1*ye[e1][s1] (ye bf16) [R6-verified] ----------------
__global__ __launch_bounds__(256) void combine_kernel(
    const unsigned short* __restrict__ ye, const int* __restrict__ a_e,
    const int* __restrict__ a_slot, const float* __restrict__ a_gate, float* __restrict__ out)
{
  int n = blockIdx.x, t = threadIdx.x;
  int e0 = a_e[n*2], e1 = a_e[n*2+1];
  int s0 = a_slot[n*2], s1 = a_slot[n*2+1];
  float g0 = a_gate[n*2], g1 = a_gate[n*2+1];
  float r[4] = {0.f, 0.f, 0.f, 0.f};
  if (s0 < CAP) {
    ushort4 v = *(const ushort4*)&ye[(size_t)(e0*CAP + s0)*DMODEL + t*4];
    r[0] += g0*bf2f(v.x); r[1] += g0*bf2f(v.y); r[2] += g0*bf2f(v.z); r[3] += g0*bf2f(v.w);
  }
  if (s1 < CAP) {
    ushort4 v = *(const ushort4*)&ye[(size_t)(e1*CAP + s1)*DMODEL + t*4];
    r[0] += g1*bf2f(v.x); r[1] += g1*bf2f(v.y); r[2] += g1*bf2f(v.z); r[3] += g1*bf2f(v.w);
  }
  float4 o; o.x = r[0]; o.y = r[1]; o.z = r[2]; o.w = r[3];
  *(float4*)&out[(size_t)n*DMODEL + t*4] = o;
}

extern "C" void kernel_launch(void* const* d_in, const int* in_sizes, int n_in,
                              void* d_out, int out_size, void* d_ws, size_t ws_size,
                              hipStream_t stream) {
  const float* x  = (const float*)d_in[0];
  const float* Wg = (const float*)d_in[1];
  const float* bg = (const float*)d_in[2];
  const float* W1 = (const float*)d_in[3];
  const float* b1 = (const float*)d_in[4];
  const float* W2 = (const float*)d_in[5];
  const float* b2 = (const float*)d_in[6];
  float* out = (float*)d_out;
  char* ws = (char*)d_ws;

  // workspace ~224MB + tables; ye overlays W1T (dead after gemm1)
  unsigned short* W1T = (unsigned short*)(ws);                 // 67,108,864 B [(e*16+rt)*16+kt] imgs
  unsigned short* W2T = (unsigned short*)(ws + 67108864);      // 67,108,864 B [(e*8+rt)*32+kt] imgs
  unsigned short* Xe  = (unsigned short*)(ws + 134217728);     // 33,554,432 B [(e*8+rt)*16+kt] imgs
  unsigned short* hB  = (unsigned short*)(ws + 167772160);     // 67,108,864 B [(e*8+mi)*32+ch] imgs
  unsigned short* ye  = (unsigned short*)(ws);                 // 33,554,432 B (overlay W1T)
  int* cnt            = (int*)(ws + 234881024);                // 64 B
  int* tok            = (int*)(ws + 234881088);                // 65,536 B
  int* a_e            = (int*)(ws + 234946624);                // 32,768 B
  int* a_slot         = (int*)(ws + 234979392);                // 32,768 B
  float* a_gate       = (float*)(ws + 235012160);              // 32,768 B

  prepack_kernel<<<4096, 256, 0, stream>>>(W2, W2T, HDIM, DMODEL);   // W2T logical [D][H]
  prepack_kernel<<<4096, 256, 0, stream>>>(W1, W1T, DMODEL, HDIM);   // W1T logical [H][D] (L3-hot)
  gate_logits_kernel<<<1024, 256, 0, stream>>>(x, Wg, bg, a_e, a_gate);
  assign_kernel<<<16, 256, 0, stream>>>(a_e, a_slot, tok, cnt);
  gather_kernel<<<8192, 256, 0, stream>>>(x, cnt, tok, Xe);
  // gemm1: Xe x W1T -> hB images + gelu; 256x256 tiles, KT=16, NTG=8
  gemm_kernel<16, 8, true,  true ><<<512, 512, 0, stream>>>(Xe, W1T, hB, b1, cnt);
  // gemm2: hB x W2T -> ye bf16 linear; 256x256 tiles, KT=32, NTG=4
  gemm_kernel<32, 4, false, false><<<256, 512, 0, stream>>>(hB, W2T, ye, b2, cnt);
  combine_kernel<<<4096, 256, 0, stream>>>(ye, a_e, a_slot, a_gate, out);
}

// Round 15
// 226.080 us; speedup vs baseline: 1.2875x; 1.2875x over previous
//
#include <hip/hip_runtime.h>

#define N_TOK 4096
#define DMODEL 1024
#define NEXP 16
#define HDIM 2048
#define CAP 1024

typedef __attribute__((ext_vector_type(8))) short frag8;      // 8 bf16 MFMA operand
typedef __attribute__((ext_vector_type(4))) float f32x4;      // MFMA accumulator
typedef __attribute__((ext_vector_type(8))) unsigned short us8;

__device__ __forceinline__ unsigned short f2bf(float x) {
  unsigned u = __builtin_bit_cast(unsigned, x);
  u += 0x7fffu + ((u >> 16) & 1u);           // RNE
  return (unsigned short)(u >> 16);
}
__device__ __forceinline__ float bf2f(unsigned short b) {
  unsigned u = ((unsigned)b) << 16;
  return __builtin_bit_cast(float, u);
}
__device__ __forceinline__ void load_lds16(const void* g, void* l) {
  __builtin_amdgcn_global_load_lds((const __attribute__((address_space(1))) void*)g,
                                   (__attribute__((address_space(3))) void*)l, 16, 0, 0);
}
#define SBAR0 __builtin_amdgcn_sched_barrier(0)

// ---------------- gate phase 1: logits -> top2 -> softmax (NO atomics) [R2-verified] ----------------
__global__ __launch_bounds__(256) void gate_logits_kernel(
    const float* __restrict__ x, const float* __restrict__ Wg, const float* __restrict__ bg,
    int* __restrict__ a_e, float* __restrict__ a_gate)
{
  int wid = threadIdx.x >> 6, l = threadIdx.x & 63;
  int n = blockIdx.x * 4 + wid;
  const float* xr = x + (size_t)n * DMODEL;
  float acc[NEXP];
#pragma unroll
  for (int e = 0; e < NEXP; ++e) acc[e] = 0.f;
#pragma unroll
  for (int q = 0; q < 4; ++q) {
    float4 xv = *(const float4*)(xr + q * 256 + l * 4);
    const float* wr = Wg + (size_t)(q * 256 + l * 4) * NEXP;
#pragma unroll
    for (int j = 0; j < 4; ++j) {
      float xs = j == 0 ? xv.x : j == 1 ? xv.y : j == 2 ? xv.z : xv.w;
      const float4* w4 = (const float4*)(wr + j * NEXP);
#pragma unroll
      for (int qq = 0; qq < 4; ++qq) {
        float4 w = w4[qq];
        acc[qq*4+0] += xs * w.x; acc[qq*4+1] += xs * w.y;
        acc[qq*4+2] += xs * w.z; acc[qq*4+3] += xs * w.w;
      }
    }
  }
#pragma unroll
  for (int e = 0; e < NEXP; ++e) {
    float v = acc[e];
#pragma unroll
    for (int off = 32; off > 0; off >>= 1) v += __shfl_xor(v, off, 64);
    acc[e] = v + bg[e];
  }
  if (l == 0) {
    int i1 = 0; float v1 = acc[0];
#pragma unroll
    for (int e = 1; e < NEXP; ++e) if (acc[e] > v1) { v1 = acc[e]; i1 = e; }
    int i2 = -1; float v2 = -1e30f;
#pragma unroll
    for (int e = 0; e < NEXP; ++e) if (e != i1 && acc[e] > v2) { v2 = acc[e]; i2 = e; }
    float e2 = __expf(v2 - v1);
    float inv = 1.f / (1.f + e2);
    a_e[n*2] = i1;   a_gate[n*2] = inv;
    a_e[n*2+1] = i2; a_gate[n*2+1] = e2 * inv;
  }
}

// ---------------- gate phase 2: per-expert slot assignment [R2-verified] ----------------
__global__ __launch_bounds__(256) void assign_kernel(
    const int* __restrict__ a_e, int* __restrict__ a_slot,
    int* __restrict__ tok_of_slot, int* __restrict__ cnt)
{
  __shared__ int c;
  if (threadIdx.x == 0) c = 0;
  __syncthreads();
  int eid = blockIdx.x;
  for (int j = threadIdx.x; j < N_TOK * 2; j += 256) {
    if (a_e[j] == eid) {
      int p = atomicAdd(&c, 1);
      a_slot[j] = p;
      if (p < CAP) tok_of_slot[eid * CAP + p] = j >> 1;
    }
  }
  __syncthreads();
  if (threadIdx.x == 0) cnt[eid] = c;
}

// ---------------- gather: x rows -> bf16 images [e][rt:8][kt:16][128][64] [R2-verified] ----------------
__global__ __launch_bounds__(256) void gather_kernel(
    const float* __restrict__ x, const int* __restrict__ cnt,
    const int* __restrict__ tok_of_slot, unsigned short* __restrict__ Xe)
{
  int rid = blockIdx.x * 2 + (threadIdx.x >> 7);
  int tl = threadIdx.x & 127;
  int e = rid >> 10, slot = rid & (CAP - 1);
  int c = cnt[e]; if (c > CAP) c = CAP;
  if (slot >= c) return;
  int tok = tok_of_slot[rid];
  const float4* xs = (const float4*)(x + (size_t)tok * DMODEL + tl * 8);
  float4 u = xs[0], v = xs[1];
  us8 p;
  p[0]=f2bf(u.x); p[1]=f2bf(u.y); p[2]=f2bf(u.z); p[3]=f2bf(u.w);
  p[4]=f2bf(v.x); p[5]=f2bf(v.y); p[6]=f2bf(v.z); p[7]=f2bf(v.w);
  int kt = tl >> 3, s = tl & 7;
  int row = slot & 127, rt = slot >> 7;
  size_t off = ((size_t)((e*8 + rt)*16 + kt)) * 8192 + (size_t)row*64 + ((s ^ (row & 7)) << 3);
  *(us8*)&Xe[off] = p;
}

// ---------------- grouped GEMM: 128x128 tile, 4 waves, BK=64, A LDS-dbuf + counted vmcnt ----------------
// R13 kernel unchanged EXCEPT the bid->(mt,nt) mapping: 4x4 supertile order within each
// expert (16 consecutive items = 4mt x 4nt) so the concurrent per-XCD working set
// (A panels ~1MB + B f32 slab ~2MB) fits the 4MB XCD L2 -> re-reads become L2 hits.
template<int KT, int NT, bool GELU, bool OUT_BLOCKED>
__global__ __launch_bounds__(256, 3) void gemm_kernel(
    const unsigned short* __restrict__ Aimg, const float* __restrict__ W,
    unsigned short* __restrict__ OutU, const float* __restrict__ bias,
    const int* __restrict__ cnt)
{
  constexpr int LDW = NT * 128;
  __shared__ __align__(16) char smem[49152];       // A0 16K | A1 16K | B 16K
  constexpr int NBLK = NEXP * 8 * NT;
  int bid = blockIdx.x;
  int item = (bid & 7) * (NBLK / 8) + (bid >> 3);  // XCD-chunked
  int e = item / (8 * NT), rem = item % (8 * NT);
  int stm = rem / (4 * NT);                        // supertile row (2 per expert)
  int r2  = rem % (4 * NT);
  int stn = r2 >> 4;                               // supertile col (NT/4 per expert)
  int r3  = r2 & 15;
  int mt  = stm * 4 + (r3 >> 2);                   // 4x4 supertile interior
  int nt  = stn * 4 + (r3 & 3);
  int mcnt = cnt[e]; if (mcnt > CAP) mcnt = CAP;
  if (mt * 128 >= mcnt) return;
  int t = threadIdx.x, l = t & 63, wid = t >> 6;
  int wm = wid >> 1, wn = wid & 1;
  int rA = l & 15, g = l >> 4, r7 = rA & 7;
  int sw0 = (g ^ r7) << 4, sw1 = ((g + 4) ^ r7) << 4;   // byte slot offsets

  const char* asrc = (const char*)(Aimg + (size_t)(e * 8 + mt) * KT * 8192);
  // B staging map: thread -> n-row (t&127), k-run 32 at (t>>7)*32
  int brow = t & 127;
  int bk0 = (t >> 7) * 32;
  int bs0 = bk0 >> 3;
  int bsig = brow & 7;
  const float* wsrc = W + (size_t)e * (KT * 64) * LDW + (size_t)nt * 128 + brow;
  float br[32];

  auto loadB = [&](int kt) {                       // 32 coalesced scalar f32
    const float* p = wsrc + (size_t)(kt * 64 + bk0) * LDW;
#pragma unroll
    for (int j = 0; j < 32; ++j) br[j] = p[(size_t)j * LDW];
  };
  auto writeB = [&]() {                            // 4x ds_write_b128, conflict-free (R12-verified)
    char* lB = smem + 32768;
#pragma unroll
    for (int c2 = 0; c2 < 4; ++c2) {
      us8 p8;
#pragma unroll
      for (int j = 0; j < 8; ++j) p8[j] = f2bf(br[c2 * 8 + j]);
      *(us8*)(lB + brow * 128 + (((bs0 + c2) ^ bsig) << 4)) = p8;
    }
  };
  auto stageA = [&](char* dst, int kt) {           // 16KB linear via 4 gload_lds
    const char* s = asrc + (size_t)kt * 16384;
    load_lds16(s + t * 16,         dst + t * 16);
    load_lds16(s + 4096 + t * 16,  dst + 4096 + t * 16);
    load_lds16(s + 8192 + t * 16,  dst + 8192 + t * 16);
    load_lds16(s + 12288 + t * 16, dst + 12288 + t * 16);
  };

  f32x4 acc[4][4] = {};
  char* A0 = smem;
  char* A1 = smem + 16384;

  auto compute = [&](const char* aBuf) {
    const char* bA = aBuf + (wm * 64 + rA) * 128;
    const char* bB = smem + 32768 + (wn * 64 + rA) * 128;
    frag8 bfr[4][2];
#pragma unroll
    for (int n16 = 0; n16 < 4; ++n16) {
      bfr[n16][0] = *(const frag8*)(bB + n16 * 2048 + sw0);
      bfr[n16][1] = *(const frag8*)(bB + n16 * 2048 + sw1);
    }
    __builtin_amdgcn_s_setprio(1);
#pragma unroll
    for (int m16 = 0; m16 < 4; ++m16) {
      frag8 a0 = *(const frag8*)(bA + m16 * 2048 + sw0);
      frag8 a1 = *(const frag8*)(bA + m16 * 2048 + sw1);
#pragma unroll
      for (int n16 = 0; n16 < 4; ++n16) {
        acc[m16][n16] = __builtin_amdgcn_mfma_f32_16x16x32_bf16(a0, bfr[n16][0], acc[m16][n16], 0, 0, 0);
        acc[m16][n16] = __builtin_amdgcn_mfma_f32_16x16x32_bf16(a1, bfr[n16][1], acc[m16][n16], 0, 0, 0);
      }
    }
    __builtin_amdgcn_s_setprio(0);
  };

  // ---- prologue. invariant at loop top (kt, cur): A[cur]=A(kt), Bbuf=B(kt),
  // in flight: [loadB(kt+1):32][stageA(A[cur^1],kt+1):4]
  loadB(0); SBAR0;
  stageA(A0, 0); SBAR0;
  asm volatile("s_waitcnt vmcnt(4)" ::: "memory");   // B(0) regs arrived
  writeB();
  loadB(1); SBAR0;
  stageA(A1, 1); SBAR0;
  asm volatile("s_waitcnt vmcnt(36)" ::: "memory");  // stageA(A0) done
  asm volatile("s_waitcnt lgkmcnt(0)" ::: "memory");
  SBAR0; __builtin_amdgcn_s_barrier(); SBAR0;

  int cur = 0;
  for (int kt = 0; kt < KT; ++kt) {
    compute(cur ? A1 : A0);
    if (kt + 1 < KT) {
      asm volatile("s_waitcnt vmcnt(4)" ::: "memory");   // loadB(kt+1) arrived (1 iter old)
      SBAR0; __builtin_amdgcn_s_barrier(); SBAR0;        // all waves done reading Bbuf & A[cur]
      writeB();                                          // B(kt+1) -> Bbuf
      int k2 = (kt + 2 < KT) ? kt + 2 : KT - 1;          // clamped: uniform vm counts
      loadB(k2); SBAR0;
      stageA(cur ? A1 : A0, k2); SBAR0;                  // overwrite A[cur]
      asm volatile("s_waitcnt vmcnt(36)" ::: "memory");  // stageA(kt+1) done (1 iter old)
      asm volatile("s_waitcnt lgkmcnt(0)" ::: "memory");
      SBAR0; __builtin_amdgcn_s_barrier(); SBAR0;        // tile kt+1 ready
      cur ^= 1;
    }
  }
  asm volatile("s_waitcnt vmcnt(0)" ::: "memory");       // drain clamped redundant DMAs
  asm volatile("s_waitcnt lgkmcnt(0)" ::: "memory");
  SBAR0; __builtin_amdgcn_s_barrier(); SBAR0;            // LDS dead; reuse as epilogue bounce

  float bv[4];
#pragma unroll
  for (int n16 = 0; n16 < 4; ++n16)
    bv[n16] = bias[e * LDW + nt * 128 + wn * 64 + n16 * 16 + rA];

  char* wb = smem + wid * 8192;                      // per-wave 64x64 bf16 bounce (8KB)
  if constexpr (OUT_BLOCKED) {
    // gelu -> bf16 -> swizzled 64x64 image -> hB images [e][mt:8][chunk:2*NT][128][64]
#pragma unroll
    for (int m16 = 0; m16 < 4; ++m16)
#pragma unroll
      for (int n16 = 0; n16 < 4; ++n16)
#pragma unroll
        for (int rr = 0; rr < 4; ++rr) {
          float xv = acc[m16][n16][rr] + bv[n16];
          if (GELU) {
            float u = 0.7978845608028654f * (xv + 0.044715f * xv * xv * xv);
            xv = xv / (1.f + __expf(-2.f * u));      // x*sigmoid(2u) == gelu_tanh
          }
          int row = m16 * 16 + g * 4 + rr;           // 0..63
          int col = n16 * 16 + rA;                   // 0..63
          *(unsigned short*)(wb + row * 128 + (((col >> 3) ^ (row & 7)) << 4) + (col & 7) * 2) = f2bf(xv);
        }
    asm volatile("s_waitcnt lgkmcnt(0)" ::: "memory");
    size_t ob = ((size_t)(e * 8 + mt) * (2 * NT) + nt * 2 + wn) * 8192;
#pragma unroll
    for (int it = 0; it < 8; ++it) {
      int row = it * 8 + (l >> 3), p = l & 7;        // phys slot == out phys slot (XORs cancel)
      us8 v = *(const us8*)(wb + row * 128 + p * 16);
      *(us8*)&OutU[ob + (size_t)(wm * 64 + row) * 64 + p * 8] = v;
    }
  } else {
    // linear bf16 out [e][CAP][LDW]
#pragma unroll
    for (int m16 = 0; m16 < 4; ++m16)
#pragma unroll
      for (int n16 = 0; n16 < 4; ++n16)
#pragma unroll
        for (int rr = 0; rr < 4; ++rr) {
          int row = m16 * 16 + g * 4 + rr;
          int col = n16 * 16 + rA;
          *(unsigned short*)(wb + row * 128 + col * 2) = f2bf(acc[m16][n16][rr] + bv[n16]);
        }
    asm volatile("s_waitcnt lgkmcnt(0)" ::: "memory");
#pragma unroll
    for (int it = 0; it < 8; ++it) {
      int row = it * 8 + (l >> 3), p = l & 7;
      us8 v = *(const us8*)(wb + row * 128 + p * 16);
      *(us8*)&OutU[(size_t)(e * CAP + mt * 128 + wm * 64 + row) * LDW
                   + nt * 128 + wn * 64 + p * 8] = v;
    }
  }
}

// ---------------- combine: out[n] = g0*ye[e0][s0] + g1*ye[e1][s1] (ye bf16) [R6-verified] ----------------
__global__ __launch_bounds__(256) void combine_kernel(
    const unsigned short* __restrict__ ye, const int* __restrict__ a_e,
    const int* __restrict__ a_slot, const float* __restrict__ a_gate, float* __restrict__ out)
{
  int n = blockIdx.x, t = threadIdx.x;
  int e0 = a_e[n*2], e1 = a_e[n*2+1];
  int s0 = a_slot[n*2], s1 = a_slot[n*2+1];
  float g0 = a_gate[n*2], g1 = a_gate[n*2+1];
  float r[4] = {0.f, 0.f, 0.f, 0.f};
  if (s0 < CAP) {
    ushort4 v = *(const ushort4*)&ye[(size_t)(e0*CAP + s0)*DMODEL + t*4];
    r[0] += g0*bf2f(v.x); r[1] += g0*bf2f(v.y); r[2] += g0*bf2f(v.z); r[3] += g0*bf2f(v.w);
  }
  if (s1 < CAP) {
    ushort4 v = *(const ushort4*)&ye[(size_t)(e1*CAP + s1)*DMODEL + t*4];
    r[0] += g1*bf2f(v.x); r[1] += g1*bf2f(v.y); r[2] += g1*bf2f(v.z); r[3] += g1*bf2f(v.w);
  }
  float4 o; o.x = r[0]; o.y = r[1]; o.z = r[2]; o.w = r[3];
  *(float4*)&out[(size_t)n*DMODEL + t*4] = o;
}

extern "C" void kernel_launch(void* const* d_in, const int* in_sizes, int n_in,
                              void* d_out, int out_size, void* d_ws, size_t ws_size,
                              hipStream_t stream) {
  const float* x  = (const float*)d_in[0];
  const float* Wg = (const float*)d_in[1];
  const float* bg = (const float*)d_in[2];
  const float* W1 = (const float*)d_in[3];
  const float* b1 = (const float*)d_in[4];
  const float* W2 = (const float*)d_in[5];
  const float* b2 = (const float*)d_in[6];
  float* out = (float*)d_out;
  char* ws = (char*)d_ws;

  // workspace ~128MB + tables (no prepack buffers)
  unsigned short* Xe = (unsigned short*)(ws);                  // 33,554,432 B [(e*8+rt)*16+kt] imgs
  unsigned short* hB = (unsigned short*)(ws + 33554432);       // 67,108,864 B [(e*8+mt)*32+ch] imgs
  unsigned short* ye = (unsigned short*)(ws + 100663296);      // 33,554,432 B [e][CAP][1024] bf16
  int* cnt           = (int*)(ws + 134217728);                 // 64 B
  int* tok           = (int*)(ws + 134217792);                 // 65,536 B
  int* a_e           = (int*)(ws + 134283328);                 // 32,768 B
  int* a_slot        = (int*)(ws + 134316096);                 // 32,768 B
  float* a_gate      = (float*)(ws + 134348864);               // 32,768 B

  gate_logits_kernel<<<1024, 256, 0, stream>>>(x, Wg, bg, a_e, a_gate);
  assign_kernel<<<16, 256, 0, stream>>>(a_e, a_slot, tok, cnt);
  gather_kernel<<<8192, 256, 0, stream>>>(x, cnt, tok, Xe);
  // gemm1: Xe x W1[e][1024][2048] -> hB images + gelu; 128x128 tiles, KT=16, NT=16
  gemm_kernel<16, 16, true,  true ><<<2048, 256, 0, stream>>>(Xe, W1, hB, b1, cnt);
  // gemm2: hB x W2[e][2048][1024] -> ye bf16 linear; 128x128 tiles, KT=32, NT=8
  gemm_kernel<32, 8,  false, false><<<1024, 256, 0, stream>>>(hB, W2, ye, b2, cnt);
  combine_kernel<<<4096, 256, 0, stream>>>(ye, a_e, a_slot, a_gate, out);
}